// Round 6
// baseline (91.896 us; speedup 1.0000x reference)
//
#include <hip/hip_runtime.h>

// Problem constants: B=4, L=512, D=128, C=128
#define NB 4
#define SL 512
#define DD 128
#define CC 128

__device__ __forceinline__ float fexp2(float x) { return __builtin_amdgcn_exp2f(x); }
__device__ __forceinline__ float frcp(float x)  { return __builtin_amdgcn_rcpf(x); }

// Kernel 1: projections, EXPONENTIATED (trans factorization):
//   E  [B*L, C]  = exp2( K2 * (inps @ wei_t + bxh) )
//   F  [B, C, L] = exp2( K2 * (inps @ wei_x) )^T
// v1 (round-0 proven, best measured): 2 rows/block, 256 threads,
// 1024 blocks = 4 blocks/CU = 4 waves/SIMD.
__global__ __launch_bounds__(256) void proj_kernel(
    const float* __restrict__ inps, const float* __restrict__ wei_t,
    const float* __restrict__ wei_x, const float* __restrict__ bxh,
    float* __restrict__ E, float* __restrict__ F)
{
    const float K2 = 2.8853900817779268f;  // 2*log2(e)
    const int row0 = blockIdx.x * 2;       // global row = b*SL + i
    const int b    = row0 >> 9;
    const int i0   = row0 & 511;
    const int c    = threadIdx.x & 127;
    const int sel  = threadIdx.x >> 7;     // wave-uniform: waves 0-1 wei_t, 2-3 wei_x

    const float* W  = sel ? wei_x : wei_t;
    const float* r0 = inps + (size_t)row0 * DD;   // uniform -> s_load
    const float* r1 = r0 + DD;

    float a0 = 0.f, a1 = 0.f;
    #pragma unroll 8
    for (int k = 0; k < DD; ++k) {
        float w = W[k * CC + c];           // coalesced across c
        a0 = fmaf(r0[k], w, a0);
        a1 = fmaf(r1[k], w, a1);
    }

    if (sel == 0) {
        float bb = bxh[c];
        E[(size_t)(row0 + 0) * CC + c] = fexp2(K2 * (a0 + bb));
        E[(size_t)(row0 + 1) * CC + c] = fexp2(K2 * (a1 + bb));
    } else {
        float2 v = {fexp2(K2 * a0), fexp2(K2 * a1)};
        *reinterpret_cast<float2*>(&F[((size_t)b * CC + c) * SL + i0]) = v;
    }
}

// Kernel 2 v6: one block per (b, 4 rows of i). 512 blocks x 512 threads.
// SINGLE change vs round-5 (90.7 us): __launch_bounds__(512, 6).
//   -> VGPR cap 85, 3 blocks/CU (LDS 42.5 KB x 3 = 127.5 <= 160),
//      24 waves/CU = 6 waves/SIMD.
// Rationale: every prior config sat on the same (waves x regs) line:
//   r0: 8 waves/SIMD @ 64 VGPR  -> 91.0
//   r4: 4 waves/SIMD @ 128 VGPR -> 96.8 (1 blk/CU)
//   r5: 4 waves/SIMD @ 128 VGPR -> 90.7
// (512,6) is the only point ABOVE that line: 6 waves @ 85 regs. If phase
// B is L2-latency-exposure-bound, +50% TLP cuts the exposed fraction.
__global__ __launch_bounds__(512, 6) void attn_kernel(
    const float* __restrict__ inps, const float* __restrict__ wei_a,
    const float* __restrict__ E, const float* __restrict__ F,
    float* __restrict__ out)
{
    __shared__ float4 upk[CC];             // E quads {E[i0..i0+3, c]}  (2 KB)
    __shared__ float pool[4 * 16 * DD];    // 32 KB: c-merge (B/C), then phase-D partials
    __shared__ float scT[SL * 4];          // a[i][j] stored [j][4]      (8 KB)
    __shared__ float redw[4 * 4];          // 4 rows x 4 waves

    const int blk = blockIdx.x;            // 512 blocks
    const int b   = blk >> 7;
    const int i0  = (blk & 127) * 4;
    const int bi0 = b * SL + i0;
    const int tid = threadIdx.x;
    const int jt  = tid & 255;             // j-pair index
    const int ch  = tid >> 8;              // c-half (wave-uniform)
    const int j0  = jt * 2;

    // Phase A: stage the four block-uniform E rows as quads (128 threads)
    if (tid < CC) {
        float4 u;
        u.x = E[(size_t)(bi0 + 0) * CC + tid];
        u.y = E[(size_t)(bi0 + 1) * CC + tid];
        u.z = E[(size_t)(bi0 + 2) * CC + tid];
        u.w = E[(size_t)(bi0 + 3) * CC + tid];
        upk[tid] = u;
    }
    __syncthreads();                       // barrier 1

    // Phase B: partial s over this thread's 64-c half, 4 i's x 2 j's.
    const int c0 = ch * 64;
    const float* fb = F + ((size_t)b * CC + c0) * SL + j0;
    const float4* up = upk + c0;
    const float* wa = wei_a + c0;          // uniform -> s_load (K$ hot)
    float sx[4] = {0.f, 0.f, 0.f, 0.f};
    float sy[4] = {0.f, 0.f, 0.f, 0.f};
    #pragma unroll 4
    for (int cp = 0; cp < 32; ++cp) {
        float2 f0 = *reinterpret_cast<const float2*>(&fb[(size_t)(2 * cp) * SL]);
        float2 f1 = *reinterpret_cast<const float2*>(&fb[(size_t)(2 * cp + 1) * SL]);
        float4 u0 = up[2 * cp];            // broadcast ds_read_b128
        float4 u1 = up[2 * cp + 1];
        float wa0 = wa[2 * cp], wa1 = wa[2 * cp + 1];
        const float* u0p = reinterpret_cast<const float*>(&u0);
        const float* u1p = reinterpret_cast<const float*>(&u1);
        #pragma unroll
        for (int i = 0; i < 4; ++i) {
            float ax = fmaf(u0p[i], f0.x, 1.0f);
            float bx = fmaf(u1p[i], f1.x, 1.0f);
            float numx = fmaf(wa0, bx, wa1 * ax);
            sx[i] = fmaf(numx, frcp(ax * bx), sx[i]);
            float ay = fmaf(u0p[i], f0.y, 1.0f);
            float by = fmaf(u1p[i], f1.y, 1.0f);
            float numy = fmaf(wa0, by, wa1 * ay);
            sy[i] = fmaf(numy, frcp(ay * by), sy[i]);
        }
    }

    // Park upper-half partials (stride 9: gcd(9,32)=1 -> 2-way max = free).
    if (ch == 1) {
        float* m = &pool[jt * 9];
        #pragma unroll
        for (int i = 0; i < 4; ++i) { m[i] = sx[i]; m[4 + i] = sy[i]; }
    }
    __syncthreads();                       // barrier 2: partials parked

    // Phase C (lower-half threads, 4 waves): merge + exp + row-sum + norm.
    if (ch == 0) {
        {
            const float* m = &pool[jt * 9];
            #pragma unroll
            for (int i = 0; i < 4; ++i) { sx[i] += m[i]; sy[i] += m[4 + i]; }
        }
        const float KE = -2.8853900817779268f;  // -2*log2(e)
        float ex[4], ey[4];
        const int lane = tid & 63, wv = tid >> 6;   // wv in 0..3
        #pragma unroll
        for (int i = 0; i < 4; ++i) {
            ex[i] = fexp2(sx[i] * KE);
            ey[i] = fexp2(sy[i] * KE);
            float t = ex[i] + ey[i];
            #pragma unroll
            for (int off = 32; off > 0; off >>= 1)
                t += __shfl_xor(t, off, 64);
            if (lane == 0) redw[i * 4 + wv] = t;
        }
        __syncthreads();                   // barrier 3
        float4 av0, av1;
        {
            float S0 = redw[0] + redw[1] + redw[2] + redw[3];
            float S1 = redw[4] + redw[5] + redw[6] + redw[7];
            float S2 = redw[8] + redw[9] + redw[10] + redw[11];
            float S3 = redw[12] + redw[13] + redw[14] + redw[15];
            float r0 = frcp(S0 + 1e-7f), r1 = frcp(S1 + 1e-7f);
            float r2 = frcp(S2 + 1e-7f), r3 = frcp(S3 + 1e-7f);
            av0 = make_float4(ex[0] * r0, ex[1] * r1, ex[2] * r2, ex[3] * r3);
            av1 = make_float4(ey[0] * r0, ey[1] * r1, ey[2] * r2, ey[3] * r3);
        }
        *reinterpret_cast<float4*>(&scT[j0 * 4])     = av0;  // a[*][j0]
        *reinterpret_cast<float4*>(&scT[j0 * 4 + 4]) = av1;  // a[*][j0+1]
    } else {
        __syncthreads();                   // barrier 3 (match)
    }
    __syncthreads();                       // barrier 4: scT ready, pool free

    // Phase D: a @ inps partials, all 512 threads.
    {
        const int dq = (tid & 31) * 4;
        const int jq = tid >> 5;           // 0..15, 32 j each
        const float* ibase = inps + (size_t)b * SL * DD;
        float4 acc0 = {0,0,0,0}, acc1 = {0,0,0,0}, acc2 = {0,0,0,0}, acc3 = {0,0,0,0};
        const int jb = jq * 32;
        #pragma unroll 4
        for (int jj = 0; jj < 32; ++jj) {
            int jx = jb + jj;
            float4 v  = *reinterpret_cast<const float4*>(ibase + (size_t)jx * DD + dq);
            float4 a4 = *reinterpret_cast<const float4*>(&scT[jx * 4]);  // broadcast
            acc0.x = fmaf(a4.x, v.x, acc0.x); acc0.y = fmaf(a4.x, v.y, acc0.y);
            acc0.z = fmaf(a4.x, v.z, acc0.z); acc0.w = fmaf(a4.x, v.w, acc0.w);
            acc1.x = fmaf(a4.y, v.x, acc1.x); acc1.y = fmaf(a4.y, v.y, acc1.y);
            acc1.z = fmaf(a4.y, v.z, acc1.z); acc1.w = fmaf(a4.y, v.w, acc1.w);
            acc2.x = fmaf(a4.z, v.x, acc2.x); acc2.y = fmaf(a4.z, v.y, acc2.y);
            acc2.z = fmaf(a4.z, v.z, acc2.z); acc2.w = fmaf(a4.z, v.w, acc2.w);
            acc3.x = fmaf(a4.w, v.x, acc3.x); acc3.y = fmaf(a4.w, v.y, acc3.y);
            acc3.z = fmaf(a4.w, v.z, acc3.z); acc3.w = fmaf(a4.w, v.w, acc3.w);
        }
        *reinterpret_cast<float4*>(&pool[(0 * 16 + jq) * DD + dq]) = acc0;
        *reinterpret_cast<float4*>(&pool[(1 * 16 + jq) * DD + dq]) = acc1;
        *reinterpret_cast<float4*>(&pool[(2 * 16 + jq) * DD + dq]) = acc2;
        *reinterpret_cast<float4*>(&pool[(3 * 16 + jq) * DD + dq]) = acc3;
    }
    __syncthreads();                       // barrier 5

    // Phase E: reduce 16 partials per (i, d), write out.
    {
        int i = tid >> 7, d = tid & 127;   // 4 rows x 128 d
        float sum = 0.f;
        #pragma unroll
        for (int q = 0; q < 16; ++q) sum += pool[(i * 16 + q) * DD + d];
        out[(size_t)(bi0 + i) * DD + d] = sum;
    }
}

extern "C" void kernel_launch(void* const* d_in, const int* in_sizes, int n_in,
                              void* d_out, int out_size, void* d_ws, size_t ws_size,
                              hipStream_t stream) {
    const float* inps  = (const float*)d_in[0];  // [B, L, D]
    const float* wei_t = (const float*)d_in[1];  // [D, C]
    const float* wei_x = (const float*)d_in[2];  // [D, C]
    const float* bxh   = (const float*)d_in[3];  // [C]
    const float* wei_a = (const float*)d_in[4];  // [C]
    // d_in[5] = bxa (scalar): uniform shift before softmax -> dropped.
    float* out = (float*)d_out;                  // [B, L, D] fp32

    float* E = (float*)d_ws;                     // [B*L, C]   1 MB
    float* F = E + (size_t)NB * SL * CC;         // [B, C, L]  1 MB

    proj_kernel<<<NB * SL / 2, 256, 0, stream>>>(inps, wei_t, wei_x, bxh, E, F);
    attn_kernel<<<NB * SL / 4, 512, 0, stream>>>(inps, wei_a, E, F, out);
}